// Round 7
// baseline (115.358 us; speedup 1.0000x reference)
//
#include <hip/hip_runtime.h>

// BEVPoolV2: out[v][c] = sum_{j<40} depth[rd[v,j]] * feat[rf[v,j]][c]
//
// R7: LDS-resident feature table. Three structurally different L2-gather
// kernels (R4/R5/R6) all plateaued at ~25-28 us -> the random L2 gather path
// itself is the floor. Remove it:
//   pre A: pairs[p] = {d fp32 (validity-folded), rf}  -- streaming, deep MLP
//   pre B: feat -> fp16, group-major fg[4][4224][16ch] (+pad)
//   main : 4 ch-groups x 125 chunks(320 vox); block=1024 thr copies its
//          147 KB feat-quarter into LDS once, then per point:
//          streamed pair + ds_read_b128 + 8 FMA. No random L2 traffic left.

typedef unsigned vuint4  __attribute__((ext_vector_type(4)));
typedef float    vfloat4 __attribute__((ext_vector_type(4)));
typedef float    vfloat2 __attribute__((ext_vector_type(2)));
typedef _Float16 vhalf4  __attribute__((ext_vector_type(4)));
typedef _Float16 vhalf8  __attribute__((ext_vector_type(8)));

#define ND_ROWS 498432
#define NF_ROWS 4224
#define MAXN_PTS 40
#define NVOX 40000
#define NPTS (NVOX * MAXN_PTS)      // 1,600,000

#define NGRP 4                      // channel groups of 16
#define GRP_U4 9216                 // padded uint4 per group = 147,456 B
#define GRP_H4 (GRP_U4 * 2)         // vhalf4 stride per group
#define CHUNK_VOX 320
#define NCHUNK 125                  // 125*320 = 40000
#define MAIN_THREADS 1024

// ---- Pre A: fold validity + depth gather once, streaming ----
__global__ __launch_bounds__(256) void build_pairs(
    const float* __restrict__ depth,
    const int* __restrict__ rdp, const int* __restrict__ rfp,
    vfloat2* __restrict__ pairs)
{
    const int i = blockIdx.x * 256 + threadIdx.x; // 6250*256 == NPTS exact
    const int rd = rdp[i], rf = rfp[i];
    const bool valid = (rd < ND_ROWS) && (rf < NF_ROWS);
    const float d = depth[min(rd, ND_ROWS - 1)];  // clamped, safe
    vfloat2 pr;
    pr.x = valid ? d : 0.0f;                      // pad row contributes 0
    pr.y = __uint_as_float((unsigned)((rf < NF_ROWS) ? rf : 0));
    pairs[i] = pr;
}

// ---- Pre B: feat fp32 -> fp16, group-major [g][row][16ch] ----
__global__ __launch_bounds__(256) void pack_feat(
    const vfloat4* __restrict__ feat4, vhalf4* __restrict__ fg)
{
    const int i = blockIdx.x * 256 + threadIdx.x; // 264*256 == 67584 exact
    const vfloat4 f = feat4[i];
    vhalf4 h;
    h.x = (_Float16)f.x; h.y = (_Float16)f.y;
    h.z = (_Float16)f.z; h.w = (_Float16)f.w;
    const int r = i >> 4, q = i & 15;             // row, channel-quad
    fg[(q >> 2) * GRP_H4 + r * 4 + (q & 3)] = h;
}

// ---- Main: LDS-resident feat quarter, streamed pairs ----
__global__ __launch_bounds__(MAIN_THREADS, 4) void BEVPoolV2_79783312491037_kernel(
    const vuint4* __restrict__ fg,
    const vfloat2* __restrict__ pairs,
    vfloat4* __restrict__ out4)
{
    __shared__ vuint4 lds4[GRP_U4]; // 147,456 B feat quarter (fp16)

    const int t = threadIdx.x;
    const int g = blockIdx.x & 3;
    const int chunk = blockIdx.x >> 2;

    // Phase 0: copy the 147 KB quarter into LDS (1 KB/wave-instr, coalesced).
    const vuint4* src = fg + g * GRP_U4;
#pragma unroll
    for (int k = 0; k < 9; ++k)
        lds4[k * MAIN_THREADS + t] = src[k * MAIN_THREADS + t];
    __syncthreads();

    // Phase 1: slot s = voxel, h = channel-octet half. 640 active threads.
    const int s = t >> 1;
    const int h = t & 1;
    if (s < CHUNK_VOX) {
        const int v = chunk * CHUNK_VOX + s;
        const vfloat2* pv = pairs + v * MAXN_PTS;
        const vhalf8* lf = (const vhalf8*)lds4;

        float acc[8] = {0, 0, 0, 0, 0, 0, 0, 0};

        // 3-stage pipeline, batch B=5: ds double-buffer + pairs 2 ahead.
        vfloat2 pb[2][5];
        vhalf8  fb[2][5];
#pragma unroll
        for (int k = 0; k < 5; ++k) pb[0][k] = pv[k];
#pragma unroll
        for (int k = 0; k < 5; ++k)
            fb[0][k] = lf[__float_as_uint(pb[0][k].y) * 2 + h];
#pragma unroll
        for (int k = 0; k < 5; ++k) pb[1][k] = pv[5 + k];

#pragma unroll
        for (int b = 0; b < 8; ++b) {
            const int cur = b & 1, nxt = cur ^ 1;
            float dcur[5];
#pragma unroll
            for (int k = 0; k < 5; ++k) dcur[k] = pb[cur][k].x;
            if (b < 7) {
#pragma unroll
                for (int k = 0; k < 5; ++k)       // ds for batch b+1
                    fb[nxt][k] = lf[__float_as_uint(pb[nxt][k].y) * 2 + h];
                if (b < 6) {
#pragma unroll
                    for (int k = 0; k < 5; ++k)   // pairs for batch b+2
                        pb[cur][k] = pv[(b + 2) * 5 + k];
                }
            }
#pragma unroll
            for (int k = 0; k < 5; ++k) {         // consume batch b
                const vhalf8 f = fb[cur][k];
#pragma unroll
                for (int i = 0; i < 8; ++i)
                    acc[i] = fmaf(dcur[k], (float)f[i], acc[i]);
            }
        }

        // voxel v, global channels [g*16 + h*8, +8) -> two float4 stores
        const int o = v * 16 + g * 4 + h * 2;
        vfloat4 lo = {acc[0], acc[1], acc[2], acc[3]};
        vfloat4 hi = {acc[4], acc[5], acc[6], acc[7]};
        __builtin_nontemporal_store(lo, &out4[o]);
        __builtin_nontemporal_store(hi, &out4[o + 1]);
    }
}

extern "C" void kernel_launch(void* const* d_in, const int* in_sizes, int n_in,
                              void* d_out, int out_size, void* d_ws, size_t ws_size,
                              hipStream_t stream)
{
    const float*   depth = (const float*)d_in[0];
    const vfloat4* feat4 = (const vfloat4*)d_in[1];
    const int*     rdp   = (const int*)d_in[2];
    const int*     rfp   = (const int*)d_in[3];
    // d_in[4] is maxn (=40), hardcoded as MAXN_PTS.
    vfloat4* out4 = (vfloat4*)d_out;

    // ws layout: [0, 12.8 MB) pairs; then fg 4*147,456 B (16B-aligned).
    vfloat2* pairs = (vfloat2*)d_ws;
    vhalf4*  fg    = (vhalf4*)((char*)d_ws + (size_t)NPTS * 8);

    build_pairs<<<NPTS / 256, 256, 0, stream>>>(depth, rdp, rfp, pairs);
    pack_feat<<<(NF_ROWS * 16) / 256, 256, 0, stream>>>(feat4, fg);

    BEVPoolV2_79783312491037_kernel<<<NGRP * NCHUNK, MAIN_THREADS, 0, stream>>>(
        (const vuint4*)fg, pairs, out4);
}

// Round 8
// 98.559 us; speedup vs baseline: 1.1704x; 1.1704x over previous
//
#include <hip/hip_runtime.h>

// BEVPoolV2: out[v][c] = sum_{j<40} depth[rd[v,j]] * feat[rf[v,j]][c]
//
// R8: barrier-free gather. R4/R5/R6 (L2-gather variants) all plateau ~25-28us;
// R7 (LDS-resident feat) regressed (1 block/CU + bank conflicts). Remaining
// structural cost: per-block stage->barrier->compute serialization. Remove it:
//   pre A: pairs[p] = {rf:16 | fp16(d):16} -- validity folded, 4 B/point,
//          pure streaming with massive memory-level parallelism.
//   pre B: feat -> fp16 rows (128 B = 1 L2 line).
//   main : no LDS, no barrier. 8 threads/voxel, 8 fp16 ch/lane. 5 batches of
//          8 points, 3-stage pipeline (pairs 2 ahead, gathers 1 ahead) ->
//          8-10 loads in flight, no lgkmcnt in the hot loop.

typedef int      vint4   __attribute__((ext_vector_type(4)));
typedef unsigned vuint4  __attribute__((ext_vector_type(4)));
typedef float    vfloat4 __attribute__((ext_vector_type(4)));
typedef _Float16 vhalf4  __attribute__((ext_vector_type(4)));
typedef _Float16 vhalf8  __attribute__((ext_vector_type(8)));

#define ND_ROWS 498432
#define NF_ROWS 4224
#define MAXN_PTS 40
#define NVOX 40000
#define NPTS (NVOX * MAXN_PTS)      // 1,600,000
#define NP4  (NPTS / 4)             // 400,000 packed vuint4... (4 pts each)

// ---- Pre A: fold validity + depth once; pack point -> 4 bytes ----
__global__ __launch_bounds__(256) void build_pairs(
    const float* __restrict__ depth,
    const vint4* __restrict__ rd4, const vint4* __restrict__ rf4,
    vuint4* __restrict__ pairs4)
{
    const int i = blockIdx.x * 256 + threadIdx.x;
    if (i >= NP4) return;
    const vint4 rd = rd4[i], rf = rf4[i];
    vuint4 o;
#pragma unroll
    for (int k = 0; k < 4; ++k) {
        const int rdk = rd[k], rfk = rf[k];
        const bool valid = (rdk < ND_ROWS) && (rfk < NF_ROWS);
        const float dl = depth[min(rdk, ND_ROWS - 1)]; // clamped, safe
        const _Float16 hd = (_Float16)(valid ? dl : 0.0f);
        unsigned short hb;
        __builtin_memcpy(&hb, &hd, 2);
        o[k] = ((unsigned)((rfk < NF_ROWS) ? rfk : 0) << 16) | (unsigned)hb;
    }
    pairs4[i] = o;
}

// ---- Pre B: feat fp32 -> fp16, row-major 128 B rows ----
__global__ __launch_bounds__(256) void pack_feat(
    const vfloat4* __restrict__ feat4, vhalf4* __restrict__ out)
{
    const int i = blockIdx.x * 256 + threadIdx.x; // 264*256 == 67584 exact
    const vfloat4 f = feat4[i];
    vhalf4 h;
    h.x = (_Float16)f.x; h.y = (_Float16)f.y;
    h.z = (_Float16)f.z; h.w = (_Float16)f.w;
    out[i] = h;
}

// ---- Main: barrier-free, pipelined gather ----
__global__ __launch_bounds__(256) void BEVPoolV2_79783312491037_kernel(
    const vuint4* __restrict__ pairs4, // 10 vuint4 per voxel
    const char* __restrict__ feat16,   // 4224 x 128 B rows
    vfloat4* __restrict__ out4)
{
    const int t = threadIdx.x;
    const int g = t >> 3;              // voxel within block (32)
    const int c8 = t & 7;              // channel octet
    const int v = blockIdx.x * 32 + g;
    const vuint4* pv = pairs4 + v * 10;
    const char* fbase = feat16 + c8 * 16;

    float acc[8] = {0, 0, 0, 0, 0, 0, 0, 0};
    vuint4 pb[3][2];                   // pairs: 3 batches resident
    vhalf8 fb[2][8];                   // feat rows: double-buffered batch of 8

    // prologue: pairs for batches 0,1; gathers for batch 0
    pb[0][0] = pv[0]; pb[0][1] = pv[1];
    pb[1][0] = pv[2]; pb[1][1] = pv[3];
#pragma unroll
    for (int k = 0; k < 8; ++k) {
        const unsigned u = pb[0][k >> 2][k & 3];
        fb[0][k] = *(const vhalf8*)(fbase + (size_t)(u >> 16) * 128);
    }

#pragma unroll
    for (int b = 0; b < 5; ++b) {
        const int cur = b & 1, nxt = cur ^ 1;
        if (b < 3) {                   // pairs for batch b+2 (2 ahead)
            pb[(b + 2) % 3][0] = pv[2 * (b + 2)];
            pb[(b + 2) % 3][1] = pv[2 * (b + 2) + 1];
        }
        if (b < 4) {                   // gathers for batch b+1 (1 ahead)
#pragma unroll
            for (int k = 0; k < 8; ++k) {
                const unsigned u = pb[(b + 1) % 3][k >> 2][k & 3];
                fb[nxt][k] = *(const vhalf8*)(fbase + (size_t)(u >> 16) * 128);
            }
        }
#pragma unroll
        for (int k = 0; k < 8; ++k) {  // consume batch b
            const unsigned u = pb[b % 3][k >> 2][k & 3];
            const unsigned short hb = (unsigned short)(u & 0xffffu);
            _Float16 hd;
            __builtin_memcpy(&hd, &hb, 2);
            const float d = (float)hd;
            const vhalf8 f = fb[cur][k];
#pragma unroll
            for (int i = 0; i < 8; ++i)
                acc[i] = fmaf(d, (float)f[i], acc[i]);
        }
    }

    const int o = v * 16 + c8 * 2;     // channels [c8*8, c8*8+8)
    vfloat4 lo = {acc[0], acc[1], acc[2], acc[3]};
    vfloat4 hi = {acc[4], acc[5], acc[6], acc[7]};
    __builtin_nontemporal_store(lo, &out4[o]);
    __builtin_nontemporal_store(hi, &out4[o + 1]);
}

extern "C" void kernel_launch(void* const* d_in, const int* in_sizes, int n_in,
                              void* d_out, int out_size, void* d_ws, size_t ws_size,
                              hipStream_t stream)
{
    const float*   depth = (const float*)d_in[0];
    const vfloat4* feat4 = (const vfloat4*)d_in[1];
    const vint4*   rd4   = (const vint4*)d_in[2];
    const vint4*   rf4   = (const vint4*)d_in[3];
    // d_in[4] is maxn (=40), hardcoded as MAXN_PTS.
    vfloat4* out4 = (vfloat4*)d_out;

    // ws: [0, 6.4 MB) packed pairs; then fp16 feat (540,672 B), 16B-aligned.
    vuint4* pairs4 = (vuint4*)d_ws;
    vhalf4* feat16 = (vhalf4*)((char*)d_ws + (size_t)NPTS * 4);

    build_pairs<<<(NP4 + 255) / 256, 256, 0, stream>>>(depth, rd4, rf4, pairs4);
    pack_feat<<<(NF_ROWS * 16) / 256, 256, 0, stream>>>(feat4, feat16);

    BEVPoolV2_79783312491037_kernel<<<NVOX / 32, 256, 0, stream>>>(
        pairs4, (const char*)feat16, out4);
}

// Round 10
// 94.922 us; speedup vs baseline: 1.2153x; 1.0383x over previous
//
#include <hip/hip_runtime.h>

// BEVPoolV2: out[v][c] = sum_{j<40} depth[rd[v,j]] * feat[rf[v,j]][c]
//
// R10 = R9 with the grid-size off-by-one fixed (1826 -> 1827 blocks; the last
// 128 point-quads were never packed and read poisoned ws). Model after R4-R8:
// cost ~= 2 cyc per random 64B L2 line per CU; fp16 feat rows = 2 lines/point
// (minimum within the 0.3875 accuracy budget).
//   pre : grid-stride; region A packs feat fp32->fp16 rows (128 B),
//         region B folds validity+depth into 4 B pairs {rf:16 | fp16 d:16}.
//   main: no LDS/barrier. 8 thr/voxel x 8 fp16 ch. 5 batches of 8 points,
//         3-stage pipeline (pairs 2 ahead, row-gathers 1 ahead).

typedef int      vint4   __attribute__((ext_vector_type(4)));
typedef unsigned vuint4  __attribute__((ext_vector_type(4)));
typedef float    vfloat4 __attribute__((ext_vector_type(4)));
typedef _Float16 vhalf4  __attribute__((ext_vector_type(4)));
typedef _Float16 vhalf8  __attribute__((ext_vector_type(8)));

#define ND_ROWS 498432
#define NF_ROWS 4224
#define MAXN_PTS 40
#define NVOX 40000
#define NPTS (NVOX * MAXN_PTS)      // 1,600,000
#define NP4  (NPTS / 4)             // 400,000 point-quads
#define NFEAT4 (NF_ROWS * 16)       // 67,584 float4 groups
#define PRE_ITEMS (NFEAT4 + NP4)    // 467,584
#define PRE_BLOCKS ((PRE_ITEMS + 255) / 256) // 1827 (ceil!)

// ---- Fused pre-kernel: [0, NFEAT4) packs feat; [NFEAT4, +NP4) builds pairs ----
__global__ __launch_bounds__(256) void pre_pack(
    const float* __restrict__ depth,
    const vfloat4* __restrict__ feat4,
    const vint4* __restrict__ rd4, const vint4* __restrict__ rf4,
    vhalf4* __restrict__ feat16, vuint4* __restrict__ pairs4)
{
    const int i = blockIdx.x * 256 + threadIdx.x;
    if (i < NFEAT4) {
        const vfloat4 f = feat4[i];
        vhalf4 h;
        h.x = (_Float16)f.x; h.y = (_Float16)f.y;
        h.z = (_Float16)f.z; h.w = (_Float16)f.w;
        feat16[i] = h;
    } else if (i < PRE_ITEMS) {
        const int p = i - NFEAT4;
        const vint4 rd = rd4[p], rf = rf4[p];
        vuint4 o;
#pragma unroll
        for (int k = 0; k < 4; ++k) {
            const int rdk = rd[k], rfk = rf[k];
            const bool valid = (rdk < ND_ROWS) && (rfk < NF_ROWS);
            const float dl = depth[min(rdk, ND_ROWS - 1)]; // clamped, safe
            const _Float16 hd = (_Float16)(valid ? dl : 0.0f);
            unsigned short hb;
            __builtin_memcpy(&hb, &hd, 2);
            o[k] = ((unsigned)((rfk < NF_ROWS) ? rfk : 0) << 16) | (unsigned)hb;
        }
        pairs4[p] = o;
    }
}

// ---- Main: barrier-free, pipelined random-row gather ----
__global__ __launch_bounds__(256) void BEVPoolV2_79783312491037_kernel(
    const vuint4* __restrict__ pairs4, // 10 vuint4 per voxel
    const char* __restrict__ feat16,   // 4224 x 128 B rows
    vfloat4* __restrict__ out4)
{
    const int t = threadIdx.x;
    const int g = t >> 3;              // voxel within block (32)
    const int c8 = t & 7;              // channel octet
    const int v = blockIdx.x * 32 + g;
    const vuint4* pv = pairs4 + v * 10;
    const char* fbase = feat16 + c8 * 16;

    float acc[8] = {0, 0, 0, 0, 0, 0, 0, 0};
    vuint4 pb[3][2];                   // pairs: 3 batches resident
    vhalf8 fb[2][8];                   // feat rows: double-buffered batch

    pb[0][0] = pv[0]; pb[0][1] = pv[1];
    pb[1][0] = pv[2]; pb[1][1] = pv[3];
#pragma unroll
    for (int k = 0; k < 8; ++k) {
        const unsigned u = pb[0][k >> 2][k & 3];
        fb[0][k] = *(const vhalf8*)(fbase + (size_t)(u >> 16) * 128);
    }

#pragma unroll
    for (int b = 0; b < 5; ++b) {
        const int cur = b & 1, nxt = cur ^ 1;
        if (b < 3) {                   // pairs for batch b+2
            pb[(b + 2) % 3][0] = pv[2 * (b + 2)];
            pb[(b + 2) % 3][1] = pv[2 * (b + 2) + 1];
        }
        if (b < 4) {                   // row gathers for batch b+1
#pragma unroll
            for (int k = 0; k < 8; ++k) {
                const unsigned u = pb[(b + 1) % 3][k >> 2][k & 3];
                fb[nxt][k] = *(const vhalf8*)(fbase + (size_t)(u >> 16) * 128);
            }
        }
#pragma unroll
        for (int k = 0; k < 8; ++k) {  // consume batch b
            const unsigned u = pb[b % 3][k >> 2][k & 3];
            const unsigned short hb = (unsigned short)(u & 0xffffu);
            _Float16 hd;
            __builtin_memcpy(&hd, &hb, 2);
            const float d = (float)hd;
            const vhalf8 f = fb[cur][k];
#pragma unroll
            for (int i = 0; i < 8; ++i)
                acc[i] = fmaf(d, (float)f[i], acc[i]);
        }
    }

    const int o = v * 16 + c8 * 2;     // channels [c8*8, c8*8+8)
    vfloat4 lo = {acc[0], acc[1], acc[2], acc[3]};
    vfloat4 hi = {acc[4], acc[5], acc[6], acc[7]};
    __builtin_nontemporal_store(lo, &out4[o]);
    __builtin_nontemporal_store(hi, &out4[o + 1]);
}

extern "C" void kernel_launch(void* const* d_in, const int* in_sizes, int n_in,
                              void* d_out, int out_size, void* d_ws, size_t ws_size,
                              hipStream_t stream)
{
    const float*   depth = (const float*)d_in[0];
    const vfloat4* feat4 = (const vfloat4*)d_in[1];
    const vint4*   rd4   = (const vint4*)d_in[2];
    const vint4*   rf4   = (const vint4*)d_in[3];
    // d_in[4] is maxn (=40), hardcoded as MAXN_PTS.
    vfloat4* out4 = (vfloat4*)d_out;

    // ws: [0, 6.4 MB) packed pairs; then fp16 feat (540,672 B), 16B-aligned.
    vuint4* pairs4 = (vuint4*)d_ws;
    vhalf4* feat16 = (vhalf4*)((char*)d_ws + (size_t)NPTS * 4);

    pre_pack<<<PRE_BLOCKS, 256, 0, stream>>>(depth, feat4, rd4, rf4,
                                             feat16, pairs4);

    BEVPoolV2_79783312491037_kernel<<<NVOX / 32, 256, 0, stream>>>(
        pairs4, (const char*)feat16, out4);
}